// Round 6
// baseline (1758.186 us; speedup 1.0000x reference)
//
#include <hip/hip_runtime.h>
#include <math.h>

#define NIMG 16
#define NQI  1000
#define NCC  80
#define NGG  200
#define RR   201      // 200 fg rows + 1 bg row
#define NR   208      // rows padded to 16*13
#define RPT  13       // rows per part-lane
#define NWG  16       // workgroups per image
#define CPW  63       // columns per WG
#define NTHR 1024
#define NITER 100
#define LDW  68       // sA row stride (floats)

#define LOG2E  1.4426950408889634f
#define SC     14.426950408889634f   /* log2(e)/EPS, EPS=0.1 */
#define U2INIT 14.426950408889634f   /* u0 = 1 in log2/EPS units */
#define NEG    -1e30f                /* finite -inf: NEG+NEG finite, no NaN */

union MS { unsigned long long u; float2 f; };

// Counter barrier (iteration 1 only). All-RELAXED protocol validated r2/r3.
__device__ __forceinline__ void img_barrier(unsigned* c, unsigned target) {
    __syncthreads();
    if (threadIdx.x == 0) {
        __hip_atomic_fetch_add(c, 1u, __ATOMIC_RELAXED, __HIP_MEMORY_SCOPE_AGENT);
        int spins = 0;
        while (__hip_atomic_load(c, __ATOMIC_RELAXED, __HIP_MEMORY_SCOPE_AGENT) < target) {
            if (++spins > (1 << 22)) break;
        }
    }
    __syncthreads();
}

extern "C" __global__ void __launch_bounds__(NTHR, 1)
ota_kernel(const float* __restrict__ logits,   // [16][1000][80]
           const float* __restrict__ pboxes,   // [16][1000][4]
           const int*   __restrict__ gcls,     // [16][200]
           const float* __restrict__ gboxes,   // [16][200][4]
           const float* __restrict__ imsz,     // [16][4]
           const float* __restrict__ imszt,    // [16][200][4]
           float* __restrict__ out,            // pi [16][201][1000] ++ matched [16][1000]
           unsigned* __restrict__ cnt,         // [16*16] barrier counters
           unsigned long long* __restrict__ pmsB, // [2][16][201][16] tagged {val, tag}
           unsigned long long* __restrict__ pmsA) // [16][201][16] iter-1 {m, s}
{
    const int tid = threadIdx.x;
    const int bid = blockIdx.x;
    const int img = (bid & 7) * 2 + ((bid >> 3) >> 4);  // 16 WGs/image on one XCD
    const int wg  = (bid >> 3) & 15;
    const int q0  = wg * CPW;
    const int ncols = min(CPW, NQI - q0);
    unsigned* myc = cnt + img * 16;

    __shared__ __align__(16) float sA[NR * LDW];   // geometry / dump tile
    __shared__ float sU[NR];    // log2-domain u (accumulated)
    __shared__ float sRM[NR];   // final row max (divisor)

    float4* sTB4 = (float4*)sA;           // [200] gt boxes / image size
    float4* sGB4 = (float4*)(sA + 800);   // [200] raw gt boxes
    float*  sGA  = sA + 1600;             // [200] raw gt areas
    int*    sCL  = (int*)(sA + 1800);     // [200] gt classes

    const float LMU2 = log2f(200.0f);     // fg log2 mu; bg: log(1+1e-8)=0 in fp32

    for (int g = tid; g < NGG; g += NTHR) {
        float4 gb = *(const float4*)(gboxes + ((size_t)img * NGG + g) * 4);
        float4 t4 = *(const float4*)(imszt  + ((size_t)img * NGG + g) * 4);
        sGB4[g] = gb;
        sTB4[g] = make_float4(gb.x / t4.x, gb.y / t4.y, gb.z / t4.z, gb.w / t4.w);
        sGA[g] = (gb.z - gb.x) * (gb.w - gb.y);
        sCL[g] = gcls[(size_t)img * NGG + g];
    }
    __syncthreads();

    const int col  = tid >> 4;   // 0..63
    const int part = tid & 15;
    const int q    = q0 + col;
    const int r0   = part * RPT;

    const float* lp = logits + ((size_t)img * NQI + q) * NCC;

    // ---- neg_sum[q] ----
    float ns = 0.f;
    if (col < ncols) {
        for (int c = part; c < NCC; c += 16) {
            float l = lp[c];
            float p = 1.f / (1.f + exp2f(-l * LOG2E));
            float spl = fmaxf(l, 0.f) + log1pf(expf(-fabsf(l)));
            ns += 0.75f * spl * p * p;
        }
    }
    #pragma unroll
    for (int k = 1; k < 16; k <<= 1) ns += __shfl_xor(ns, k);

    // ---- E in registers: e[i] = -loss[r0+i][q] * SC ----
    float e[RPT];
    {
        float4 isz = *(const float4*)(imsz + img * 4);
        float4 pp = make_float4(0.f, 0.f, 0.f, 0.f);
        float ab = 0.f, ob0 = 0.f, ob1 = 0.f, ob2 = 0.f, ob3 = 0.f;
        if (col < ncols) {
            pp = *(const float4*)(pboxes + ((size_t)img * NQI + q) * 4);
            ab  = (pp.z - pp.x) * (pp.w - pp.y);
            ob0 = pp.x / isz.x; ob1 = pp.y / isz.y; ob2 = pp.z / isz.z; ob3 = pp.w / isz.w;
        }
        #pragma unroll
        for (int i = 0; i < RPT; ++i) {
            int g = r0 + i;
            float val = NEG;
            if (col < ncols) {
                if (g < NGG) {
                    float l = lp[sCL[g]];
                    float p = 1.f / (1.f + exp2f(-l * LOG2E));
                    float t0 = log1pf(expf(-fabsf(l)));
                    float spl  = fmaxf(l, 0.f) + t0;
                    float spml = spl - l;
                    float pos = 0.25f * spml * (1.f - p) * (1.f - p);
                    float neg = 0.75f * spl * p * p;
                    float lcls = ns + (pos - neg);
                    float4 tb = sTB4[g];
                    float cb = fabsf(tb.x - ob0) + fabsf(tb.y - ob1)
                             + fabsf(tb.z - ob2) + fabsf(tb.w - ob3);
                    float4 gb = sGB4[g];
                    float iwd = fminf(gb.z, pp.z) - fmaxf(gb.x, pp.x);
                    float ihd = fminf(gb.w, pp.w) - fmaxf(gb.y, pp.y);
                    float inter = fmaxf(iwd, 0.f) * fmaxf(ihd, 0.f);
                    float uni = sGA[g] + ab - inter;
                    float iou = inter / uni;
                    float cwd = fmaxf(gb.z, pp.z) - fminf(gb.x, pp.x);
                    float chd = fmaxf(gb.w, pp.w) - fminf(gb.y, pp.y);
                    float ac = fmaxf(cwd, 0.f) * fmaxf(chd, 0.f);
                    float giou = iou - (ac - uni) / ac;
                    float loss = 2.f * lcls + 5.f * cb - 2.f * giou;
                    val = -loss * SC;
                } else if (g == NGG) {
                    val = -ns * SC;
                }
            }
            e[i] = val;
        }
    }
    __syncthreads();   // geometry fully read before first dump

    const int r2 = tid >> 2, h = tid & 3;
    const int r2c = min(r2, RR - 1);

    // ==== ITERATION 1: log-domain, max-shifted (unbounded spread from u0) ====
    float vv;
    {
        float M = NEG; float xr[RPT];
        #pragma unroll
        for (int i = 0; i < RPT; ++i) { xr[i] = e[i] + U2INIT; M = fmaxf(M, xr[i]); }
        #pragma unroll
        for (int k = 1; k < 16; k <<= 1) M = fmaxf(M, __shfl_xor(M, k));
        float S = 0.f;
        #pragma unroll
        for (int i = 0; i < RPT; ++i) S += exp2f(xr[i] - M);
        #pragma unroll
        for (int k = 1; k < 16; k <<= 1) S += __shfl_xor(S, k);
        vv = -(M + log2f(S));          // v1
        if (col >= ncols) vv = NEG;
    }
    #pragma unroll
    for (int i = 0; i < RPT; ++i) sA[(r0 + i) * LDW + col] = e[i] + vv;
    __syncthreads();
    if (r2 < RR) {   // per-WG row (m,s) in log domain
        const float4* base = (const float4*)(sA + r2 * LDW + h * 16);
        float4 t0 = base[0], t1 = base[1], t2 = base[2], t3 = base[3];
        float M2 = fmaxf(
            fmaxf(fmaxf(fmaxf(t0.x, t0.y), fmaxf(t0.z, t0.w)),
                  fmaxf(fmaxf(t1.x, t1.y), fmaxf(t1.z, t1.w))),
            fmaxf(fmaxf(fmaxf(t2.x, t2.y), fmaxf(t2.z, t2.w)),
                  fmaxf(fmaxf(t3.x, t3.y), fmaxf(t3.z, t3.w))));
        #pragma unroll
        for (int k = 1; k < 4; k <<= 1) M2 = fmaxf(M2, __shfl_xor(M2, k));
        float S2 = exp2f(t0.x - M2) + exp2f(t0.y - M2) + exp2f(t0.z - M2) + exp2f(t0.w - M2)
                 + exp2f(t1.x - M2) + exp2f(t1.y - M2) + exp2f(t1.z - M2) + exp2f(t1.w - M2)
                 + exp2f(t2.x - M2) + exp2f(t2.y - M2) + exp2f(t2.z - M2) + exp2f(t2.w - M2)
                 + exp2f(t3.x - M2) + exp2f(t3.y - M2) + exp2f(t3.z - M2) + exp2f(t3.w - M2);
        #pragma unroll
        for (int k = 1; k < 4; k <<= 1) S2 += __shfl_xor(S2, k);
        if (h == 0) {
            MS ms; ms.f.x = M2; ms.f.y = S2;
            __hip_atomic_store(&pmsA[((size_t)img * RR + r2) * NWG + wg], ms.u,
                               __ATOMIC_RELAXED, __HIP_MEMORY_SCOPE_AGENT);
        }
    }
    img_barrier(myc, NWG);
    if (r2 < NR) {
        if (r2 < RR) {
            unsigned long long* pr = pmsA + ((size_t)img * RR + r2) * NWG + h * 4;
            MS a0, a1, a2, a3;
            a0.u = __hip_atomic_load(&pr[0], __ATOMIC_RELAXED, __HIP_MEMORY_SCOPE_AGENT);
            a1.u = __hip_atomic_load(&pr[1], __ATOMIC_RELAXED, __HIP_MEMORY_SCOPE_AGENT);
            a2.u = __hip_atomic_load(&pr[2], __ATOMIC_RELAXED, __HIP_MEMORY_SCOPE_AGENT);
            a3.u = __hip_atomic_load(&pr[3], __ATOMIC_RELAXED, __HIP_MEMORY_SCOPE_AGENT);
            float gm = fmaxf(fmaxf(a0.f.x, a1.f.x), fmaxf(a2.f.x, a3.f.x));
            #pragma unroll
            for (int k = 1; k < 4; k <<= 1) gm = fmaxf(gm, __shfl_xor(gm, k));
            float S = a0.f.y * exp2f(a0.f.x - gm) + a1.f.y * exp2f(a1.f.x - gm)
                    + a2.f.y * exp2f(a2.f.x - gm) + a3.f.y * exp2f(a3.f.x - gm);
            #pragma unroll
            for (int k = 1; k < 4; k <<= 1) S += __shfl_xor(S, k);
            if (h == 0) sU[r2] = (r2 < NGG ? LMU2 : 0.f) - (gm + log2f(S));  // u1
        } else if (h == 0) sU[r2] = NEG;   // pad rows stay dead
    }
    __syncthreads();

    // ==== ITERATIONS 2..100: semi-linear (plan re-derived FRESH from logs
    // every iteration -> no multiplicative history, no FTZ permanent death).
    // Bounds: plan entry <= 200 (rows sum to 200 post-u) so exp2 never
    // overflows; cs in [0.2, 4.1e4]; R in [5e-6, 1000]. ====
    for (int it = 2; it <= NITER; ++it) {
        const float tagf = (float)it;
        // v-step: t = exp2(e+u+v) fresh; colsum; vv -= log2(cs)
        float t[RPT]; float cs = 0.f;
        #pragma unroll
        for (int i = 0; i < RPT; ++i) {
            t[i] = exp2f(e[i] + sU[r0 + i] + vv);
            cs += t[i];
        }
        #pragma unroll
        for (int k = 1; k < 16; k <<= 1) cs += __shfl_xor(cs, k);
        float cf = 0.f;
        if (col < ncols) { vv -= log2f(cs); cf = 1.0f / cs; }
        #pragma unroll
        for (int i = 0; i < RPT; ++i) sA[(r0 + i) * LDW + col] = t[i] * cf;
        __syncthreads();
        // u-step: plain row sums, tagged publish (parity dbuf), poll, log2
        unsigned long long* slot =
            pmsB + (((size_t)(it & 1) * NIMG + img) * RR + r2c) * NWG;
        if (r2 < RR) {
            const float4* base = (const float4*)(sA + r2 * LDW + h * 16);
            float4 t0 = base[0], t1 = base[1], t2 = base[2], t3 = base[3];
            float s = (t0.x + t0.y + t0.z + t0.w) + (t1.x + t1.y + t1.z + t1.w)
                    + (t2.x + t2.y + t2.z + t2.w) + (t3.x + t3.y + t3.z + t3.w);
            s += __shfl_xor(s, 1); s += __shfl_xor(s, 2);
            if (h == 0) {
                MS ms; ms.f.x = s; ms.f.y = tagf;
                __hip_atomic_store(&slot[wg], ms.u,
                                   __ATOMIC_RELAXED, __HIP_MEMORY_SCOPE_AGENT);
            }
            unsigned long long* pr = slot + 4 * h;
            MS a0, a1, a2, a3;
            int spins = 0;
            for (;;) {
                a0.u = __hip_atomic_load(&pr[0], __ATOMIC_RELAXED, __HIP_MEMORY_SCOPE_AGENT);
                a1.u = __hip_atomic_load(&pr[1], __ATOMIC_RELAXED, __HIP_MEMORY_SCOPE_AGENT);
                a2.u = __hip_atomic_load(&pr[2], __ATOMIC_RELAXED, __HIP_MEMORY_SCOPE_AGENT);
                a3.u = __hip_atomic_load(&pr[3], __ATOMIC_RELAXED, __HIP_MEMORY_SCOPE_AGENT);
                if ((a0.f.y == tagf) && (a1.f.y == tagf) &&
                    (a2.f.y == tagf) && (a3.f.y == tagf)) break;
                if (++spins > (1 << 22)) break;
            }
            float R = (a0.f.x + a1.f.x) + (a2.f.x + a3.f.x);
            R += __shfl_xor(R, 1); R += __shfl_xor(R, 2);
            if (h == 0) sU[r2] += (r2 < NGG ? LMU2 : 0.f) - log2f(R);
        }
        __syncthreads();
    }

    // ==== final plan (fresh) -> rowmax -> pn -> outputs ====
    float p[RPT];
    #pragma unroll
    for (int i = 0; i < RPT; ++i) p[i] = exp2f(e[i] + sU[r0 + i] + vv);
    #pragma unroll
    for (int i = 0; i < RPT; ++i) sA[(r0 + i) * LDW + col] = p[i];
    __syncthreads();
    {
        const float tagf = (float)(NITER + 1);  // parity 1; tag-99 slots dead (proof in r4)
        unsigned long long* slot =
            pmsB + (((size_t)((NITER + 1) & 1) * NIMG + img) * RR + r2c) * NWG;
        if (r2 < RR) {
            const float4* base = (const float4*)(sA + r2 * LDW + h * 16);
            float4 t0 = base[0], t1 = base[1], t2 = base[2], t3 = base[3];
            float M2 = fmaxf(
                fmaxf(fmaxf(fmaxf(t0.x, t0.y), fmaxf(t0.z, t0.w)),
                      fmaxf(fmaxf(t1.x, t1.y), fmaxf(t1.z, t1.w))),
                fmaxf(fmaxf(fmaxf(t2.x, t2.y), fmaxf(t2.z, t2.w)),
                      fmaxf(fmaxf(t3.x, t3.y), fmaxf(t3.z, t3.w))));
            #pragma unroll
            for (int k = 1; k < 4; k <<= 1) M2 = fmaxf(M2, __shfl_xor(M2, k));
            if (h == 0) {
                MS ms; ms.f.x = M2; ms.f.y = tagf;
                __hip_atomic_store(&slot[wg], ms.u,
                                   __ATOMIC_RELAXED, __HIP_MEMORY_SCOPE_AGENT);
            }
            unsigned long long* pr = slot + 4 * h;
            MS a0, a1, a2, a3;
            int spins = 0;
            for (;;) {
                a0.u = __hip_atomic_load(&pr[0], __ATOMIC_RELAXED, __HIP_MEMORY_SCOPE_AGENT);
                a1.u = __hip_atomic_load(&pr[1], __ATOMIC_RELAXED, __HIP_MEMORY_SCOPE_AGENT);
                a2.u = __hip_atomic_load(&pr[2], __ATOMIC_RELAXED, __HIP_MEMORY_SCOPE_AGENT);
                a3.u = __hip_atomic_load(&pr[3], __ATOMIC_RELAXED, __HIP_MEMORY_SCOPE_AGENT);
                if ((a0.f.y == tagf) && (a1.f.y == tagf) &&
                    (a2.f.y == tagf) && (a3.f.y == tagf)) break;
                if (++spins > (1 << 22)) break;
            }
            float M = fmaxf(fmaxf(a0.f.x, a1.f.x), fmaxf(a2.f.x, a3.f.x));
            #pragma unroll
            for (int k = 1; k < 4; k <<= 1) M = fmaxf(M, __shfl_xor(M, k));
            if (h == 0) sRM[r2] = M;
        } else if (r2 < NR && h == 0) sRM[r2] = 1.0f;
        __syncthreads();
    }

    // argmax per column. pn by TRUE DIVISION (rowmax cell exactly 1.0, like
    // ref's pi / pi.max); strict > + min-index ties = numpy first-index.
    {
        float bv = -1.0f; int bi = 0x7fffffff;
        #pragma unroll
        for (int i = 0; i < RPT; ++i) {
            int r = r0 + i;
            float pv = p[i] / sRM[r];
            if (r < RR && pv > bv) { bv = pv; bi = r; }
        }
        #pragma unroll
        for (int k = 1; k < 16; k <<= 1) {
            float ov = __shfl_xor(bv, k); int oi = __shfl_xor(bi, k);
            if (ov > bv || (ov == bv && oi < bi)) { bv = ov; bi = oi; }
        }
        if (part == 0 && col < ncols)
            out[(size_t)NIMG * RR * NQI + (size_t)img * NQI + q] = (float)bi;
    }

    // pi output: sA already holds p in [row][col]; transpose-read with
    // division by row max (broadcast LDS read), 256B coalesced row stores.
    {
        int colj = tid & 63, rl = tid >> 6;
        #pragma unroll
        for (int tt = 0; tt < RPT; ++tt) {
            int rg = rl + 16 * tt;
            if (rg < RR && colj < ncols)
                out[((size_t)img * RR + rg) * NQI + (q0 + colj)] =
                    sA[rg * LDW + colj] / sRM[rg];
        }
    }
}

extern "C" void kernel_launch(void* const* d_in, const int* in_sizes, int n_in,
                              void* d_out, int out_size, void* d_ws, size_t ws_size,
                              hipStream_t stream) {
    const float* logits = (const float*)d_in[0];
    const float* pboxes = (const float*)d_in[1];
    const int*   gcls   = (const int*)  d_in[2];
    const float* gboxes = (const float*)d_in[3];
    const float* imsz   = (const float*)d_in[4];
    const float* imszt  = (const float*)d_in[5];
    float* out = (float*)d_out;

    // layout: cnt 1024 | pmsB[2 parities] 823,296 | pmsA 411,648
    unsigned* cnt = (unsigned*)d_ws;
    unsigned long long* pmsB = (unsigned long long*)((char*)d_ws + 1024);
    unsigned long long* pmsA =
        (unsigned long long*)((char*)d_ws + 1024 + 2ull * NIMG * RR * NWG * 8);

    // zero counters + both pmsB parity buffers' tags every call
    hipMemsetAsync(d_ws, 0, 1024 + 2ull * NIMG * RR * NWG * 8, stream);

    ota_kernel<<<dim3(256), dim3(NTHR), 0, stream>>>(
        logits, pboxes, gcls, gboxes, imsz, imszt, out, cnt, pmsB, pmsA);
}

// Round 7
// 540.767 us; speedup vs baseline: 3.2513x; 3.2513x over previous
//
#include <hip/hip_runtime.h>
#include <math.h>

#define NIMG 16
#define NQI  1000
#define NCC  80
#define NGG  200
#define RR   201      // 200 fg rows + 1 bg row
#define NR   208      // rows padded to 16*13
#define RPT  13       // rows per part-lane
#define NWG  16       // workgroups per image
#define CPW  63       // columns per WG
#define NTHR 1024
#define NITER 100
#define LDW  68       // sA row stride (floats)

#define LOG2E  1.4426950408889634f
#define SC     14.426950408889634f   /* log2(e)/EPS, EPS=0.1 */
#define U2INIT 14.426950408889634f   /* u0 = 1 in log2/EPS units */
#define NEG    -1e30f                /* finite -inf: NEG+NEG finite, no NaN */

union MS { unsigned long long u; float2 f; };

// Single-poller counter barrier (validated r2/r3: 5.3us/iter total; r6 showed
// the distributed-poll alternative congests L3 -> 17.5us/iter, FETCH 6x).
// All-RELAXED: __syncthreads drains vmcnt, so agent-scope partial stores are
// at the coherence point before thread 0's counter add becomes visible.
__device__ __forceinline__ void img_barrier(unsigned* c, unsigned target) {
    __syncthreads();
    if (threadIdx.x == 0) {
        __hip_atomic_fetch_add(c, 1u, __ATOMIC_RELAXED, __HIP_MEMORY_SCOPE_AGENT);
        int spins = 0;
        while (__hip_atomic_load(c, __ATOMIC_RELAXED, __HIP_MEMORY_SCOPE_AGENT) < target) {
            if (++spins > (1 << 22)) break;   // safety valve: never hard-hang
        }
    }
    __syncthreads();
}

extern "C" __global__ void __launch_bounds__(NTHR, 1)
ota_kernel(const float* __restrict__ logits,   // [16][1000][80]
           const float* __restrict__ pboxes,   // [16][1000][4]
           const int*   __restrict__ gcls,     // [16][200]
           const float* __restrict__ gboxes,   // [16][200][4]
           const float* __restrict__ imsz,     // [16][4]
           const float* __restrict__ imszt,    // [16][200][4]
           float* __restrict__ out,            // pi [16][201][1000] ++ matched [16][1000]
           unsigned* __restrict__ cnt,         // [16*16] barrier counters
           float* __restrict__ pmsR,           // [16][201][16] f32 rowsum partials
           unsigned long long* __restrict__ pmsA, // [16][201][16] iter-1 {m, s}
           float* __restrict__ pmx)            // [16][201][16] rowmax partials (aliases pmsA)
{
    const int tid = threadIdx.x;
    const int bid = blockIdx.x;
    const int img = (bid & 7) * 2 + ((bid >> 3) >> 4);  // 16 WGs/image on one XCD
    const int wg  = (bid >> 3) & 15;
    const int q0  = wg * CPW;
    const int ncols = min(CPW, NQI - q0);
    unsigned* myc = cnt + img * 16;

    __shared__ __align__(16) float sA[NR * LDW];   // geometry / dump tile
    __shared__ float sU[NR];    // log2-domain u (accumulated)
    __shared__ float sRM[NR];   // final row max (divisor)

    float4* sTB4 = (float4*)sA;           // [200] gt boxes / image size
    float4* sGB4 = (float4*)(sA + 800);   // [200] raw gt boxes
    float*  sGA  = sA + 1600;             // [200] raw gt areas
    int*    sCL  = (int*)(sA + 1800);     // [200] gt classes

    const float LMU2 = log2f(200.0f);     // fg log2 mu; bg: log(1+1e-8)=0 in fp32

    for (int g = tid; g < NGG; g += NTHR) {
        float4 gb = *(const float4*)(gboxes + ((size_t)img * NGG + g) * 4);
        float4 t4 = *(const float4*)(imszt  + ((size_t)img * NGG + g) * 4);
        sGB4[g] = gb;
        sTB4[g] = make_float4(gb.x / t4.x, gb.y / t4.y, gb.z / t4.z, gb.w / t4.w);
        sGA[g] = (gb.z - gb.x) * (gb.w - gb.y);
        sCL[g] = gcls[(size_t)img * NGG + g];
    }
    __syncthreads();

    const int col  = tid >> 4;   // 0..63
    const int part = tid & 15;
    const int q    = q0 + col;
    const int r0   = part * RPT;

    const float* lp = logits + ((size_t)img * NQI + q) * NCC;

    // ---- neg_sum[q] ----
    float ns = 0.f;
    if (col < ncols) {
        for (int c = part; c < NCC; c += 16) {
            float l = lp[c];
            float p = 1.f / (1.f + exp2f(-l * LOG2E));
            float spl = fmaxf(l, 0.f) + log1pf(expf(-fabsf(l)));
            ns += 0.75f * spl * p * p;
        }
    }
    #pragma unroll
    for (int k = 1; k < 16; k <<= 1) ns += __shfl_xor(ns, k);

    // ---- E in registers: e[i] = -loss[r0+i][q] * SC ----
    float e[RPT];
    {
        float4 isz = *(const float4*)(imsz + img * 4);
        float4 pp = make_float4(0.f, 0.f, 0.f, 0.f);
        float ab = 0.f, ob0 = 0.f, ob1 = 0.f, ob2 = 0.f, ob3 = 0.f;
        if (col < ncols) {
            pp = *(const float4*)(pboxes + ((size_t)img * NQI + q) * 4);
            ab  = (pp.z - pp.x) * (pp.w - pp.y);
            ob0 = pp.x / isz.x; ob1 = pp.y / isz.y; ob2 = pp.z / isz.z; ob3 = pp.w / isz.w;
        }
        #pragma unroll
        for (int i = 0; i < RPT; ++i) {
            int g = r0 + i;
            float val = NEG;
            if (col < ncols) {
                if (g < NGG) {
                    float l = lp[sCL[g]];
                    float p = 1.f / (1.f + exp2f(-l * LOG2E));
                    float t0 = log1pf(expf(-fabsf(l)));
                    float spl  = fmaxf(l, 0.f) + t0;
                    float spml = spl - l;
                    float pos = 0.25f * spml * (1.f - p) * (1.f - p);
                    float neg = 0.75f * spl * p * p;
                    float lcls = ns + (pos - neg);
                    float4 tb = sTB4[g];
                    float cb = fabsf(tb.x - ob0) + fabsf(tb.y - ob1)
                             + fabsf(tb.z - ob2) + fabsf(tb.w - ob3);
                    float4 gb = sGB4[g];
                    float iwd = fminf(gb.z, pp.z) - fmaxf(gb.x, pp.x);
                    float ihd = fminf(gb.w, pp.w) - fmaxf(gb.y, pp.y);
                    float inter = fmaxf(iwd, 0.f) * fmaxf(ihd, 0.f);
                    float uni = sGA[g] + ab - inter;
                    float iou = inter / uni;
                    float cwd = fmaxf(gb.z, pp.z) - fminf(gb.x, pp.x);
                    float chd = fmaxf(gb.w, pp.w) - fminf(gb.y, pp.y);
                    float ac = fmaxf(cwd, 0.f) * fmaxf(chd, 0.f);
                    float giou = iou - (ac - uni) / ac;
                    float loss = 2.f * lcls + 5.f * cb - 2.f * giou;
                    val = -loss * SC;
                } else if (g == NGG) {
                    val = -ns * SC;
                }
            }
            e[i] = val;
        }
    }
    __syncthreads();   // geometry fully read before first dump

    const int r2 = tid >> 2, h = tid & 3;

    // ==== ITERATION 1: log-domain, max-shifted (unbounded spread from u0) ====
    float vv;
    {
        float M = NEG; float xr[RPT];
        #pragma unroll
        for (int i = 0; i < RPT; ++i) { xr[i] = e[i] + U2INIT; M = fmaxf(M, xr[i]); }
        #pragma unroll
        for (int k = 1; k < 16; k <<= 1) M = fmaxf(M, __shfl_xor(M, k));
        float S = 0.f;
        #pragma unroll
        for (int i = 0; i < RPT; ++i) S += exp2f(xr[i] - M);
        #pragma unroll
        for (int k = 1; k < 16; k <<= 1) S += __shfl_xor(S, k);
        vv = -(M + log2f(S));          // v1
        if (col >= ncols) vv = NEG;
    }
    #pragma unroll
    for (int i = 0; i < RPT; ++i) sA[(r0 + i) * LDW + col] = e[i] + vv;
    __syncthreads();
    if (r2 < RR) {   // per-WG row (m,s) in log domain
        const float4* base = (const float4*)(sA + r2 * LDW + h * 16);
        float4 t0 = base[0], t1 = base[1], t2 = base[2], t3 = base[3];
        float M2 = fmaxf(
            fmaxf(fmaxf(fmaxf(t0.x, t0.y), fmaxf(t0.z, t0.w)),
                  fmaxf(fmaxf(t1.x, t1.y), fmaxf(t1.z, t1.w))),
            fmaxf(fmaxf(fmaxf(t2.x, t2.y), fmaxf(t2.z, t2.w)),
                  fmaxf(fmaxf(t3.x, t3.y), fmaxf(t3.z, t3.w))));
        #pragma unroll
        for (int k = 1; k < 4; k <<= 1) M2 = fmaxf(M2, __shfl_xor(M2, k));
        float S2 = exp2f(t0.x - M2) + exp2f(t0.y - M2) + exp2f(t0.z - M2) + exp2f(t0.w - M2)
                 + exp2f(t1.x - M2) + exp2f(t1.y - M2) + exp2f(t1.z - M2) + exp2f(t1.w - M2)
                 + exp2f(t2.x - M2) + exp2f(t2.y - M2) + exp2f(t2.z - M2) + exp2f(t2.w - M2)
                 + exp2f(t3.x - M2) + exp2f(t3.y - M2) + exp2f(t3.z - M2) + exp2f(t3.w - M2);
        #pragma unroll
        for (int k = 1; k < 4; k <<= 1) S2 += __shfl_xor(S2, k);
        if (h == 0) {
            MS ms; ms.f.x = M2; ms.f.y = S2;
            __hip_atomic_store(&pmsA[((size_t)img * RR + r2) * NWG + wg], ms.u,
                               __ATOMIC_RELAXED, __HIP_MEMORY_SCOPE_AGENT);
        }
    }
    img_barrier(myc, NWG);
    if (r2 < NR) {
        if (r2 < RR) {
            unsigned long long* pr = pmsA + ((size_t)img * RR + r2) * NWG + h * 4;
            MS a0, a1, a2, a3;
            a0.u = __hip_atomic_load(&pr[0], __ATOMIC_RELAXED, __HIP_MEMORY_SCOPE_AGENT);
            a1.u = __hip_atomic_load(&pr[1], __ATOMIC_RELAXED, __HIP_MEMORY_SCOPE_AGENT);
            a2.u = __hip_atomic_load(&pr[2], __ATOMIC_RELAXED, __HIP_MEMORY_SCOPE_AGENT);
            a3.u = __hip_atomic_load(&pr[3], __ATOMIC_RELAXED, __HIP_MEMORY_SCOPE_AGENT);
            float gm = fmaxf(fmaxf(a0.f.x, a1.f.x), fmaxf(a2.f.x, a3.f.x));
            #pragma unroll
            for (int k = 1; k < 4; k <<= 1) gm = fmaxf(gm, __shfl_xor(gm, k));
            float S = a0.f.y * exp2f(a0.f.x - gm) + a1.f.y * exp2f(a1.f.x - gm)
                    + a2.f.y * exp2f(a2.f.x - gm) + a3.f.y * exp2f(a3.f.x - gm);
            #pragma unroll
            for (int k = 1; k < 4; k <<= 1) S += __shfl_xor(S, k);
            if (h == 0) sU[r2] = (r2 < NGG ? LMU2 : 0.f) - (gm + log2f(S));  // u1
        } else if (h == 0) sU[r2] = NEG;   // pad rows stay dead
    }
    __syncthreads();

    // ==== ITERATIONS 2..100: semi-linear (plan re-derived FRESH from log
    // state each iteration -> no multiplicative history, no FTZ death; r6
    // validated the math). Bounds: entry <= 200, cs in [0.2,4.1e4],
    // R in [5e-6,1000]. Sync = single-poller counter barrier. ====
    for (int it = 2; it <= NITER; ++it) {
        // v-step: t = exp2(e+u+v) fresh; colsum; vv -= log2(cs)
        float t[RPT]; float cs = 0.f;
        #pragma unroll
        for (int i = 0; i < RPT; ++i) {
            t[i] = exp2f(e[i] + sU[r0 + i] + vv);
            cs += t[i];
        }
        #pragma unroll
        for (int k = 1; k < 16; k <<= 1) cs += __shfl_xor(cs, k);
        float cf = 0.f;
        if (col < ncols) { vv -= log2f(cs); cf = 1.0f / cs; }
        #pragma unroll
        for (int i = 0; i < RPT; ++i) sA[(r0 + i) * LDW + col] = t[i] * cf;
        __syncthreads();
        // u-step: per-WG row sums -> 4B f32 partial -> barrier -> combine
        if (r2 < RR) {
            const float4* base = (const float4*)(sA + r2 * LDW + h * 16);
            float4 t0 = base[0], t1 = base[1], t2 = base[2], t3 = base[3];
            float s = (t0.x + t0.y + t0.z + t0.w) + (t1.x + t1.y + t1.z + t1.w)
                    + (t2.x + t2.y + t2.z + t2.w) + (t3.x + t3.y + t3.z + t3.w);
            s += __shfl_xor(s, 1); s += __shfl_xor(s, 2);
            if (h == 0)
                __hip_atomic_store(&pmsR[((size_t)img * RR + r2) * NWG + wg], s,
                                   __ATOMIC_RELAXED, __HIP_MEMORY_SCOPE_AGENT);
        }
        img_barrier(myc, (unsigned)NWG * it);
        if (r2 < RR) {
            const float* pr = pmsR + ((size_t)img * RR + r2) * NWG + h * 4;
            float R = (__hip_atomic_load(&pr[0], __ATOMIC_RELAXED, __HIP_MEMORY_SCOPE_AGENT)
                     + __hip_atomic_load(&pr[1], __ATOMIC_RELAXED, __HIP_MEMORY_SCOPE_AGENT))
                    + (__hip_atomic_load(&pr[2], __ATOMIC_RELAXED, __HIP_MEMORY_SCOPE_AGENT)
                     + __hip_atomic_load(&pr[3], __ATOMIC_RELAXED, __HIP_MEMORY_SCOPE_AGENT));
            R += __shfl_xor(R, 1); R += __shfl_xor(R, 2);
            if (h == 0) sU[r2] += (r2 < NGG ? LMU2 : 0.f) - log2f(R);
        }
        __syncthreads();
    }

    // ==== final plan (fresh) -> rowmax -> outputs ====
    float p[RPT];
    #pragma unroll
    for (int i = 0; i < RPT; ++i) p[i] = exp2f(e[i] + sU[r0 + i] + vv);
    #pragma unroll
    for (int i = 0; i < RPT; ++i) sA[(r0 + i) * LDW + col] = p[i];
    __syncthreads();
    if (r2 < RR) {
        const float4* base = (const float4*)(sA + r2 * LDW + h * 16);
        float4 t0 = base[0], t1 = base[1], t2 = base[2], t3 = base[3];
        float M2 = fmaxf(
            fmaxf(fmaxf(fmaxf(t0.x, t0.y), fmaxf(t0.z, t0.w)),
                  fmaxf(fmaxf(t1.x, t1.y), fmaxf(t1.z, t1.w))),
            fmaxf(fmaxf(fmaxf(t2.x, t2.y), fmaxf(t2.z, t2.w)),
                  fmaxf(fmaxf(t3.x, t3.y), fmaxf(t3.z, t3.w))));
        #pragma unroll
        for (int k = 1; k < 4; k <<= 1) M2 = fmaxf(M2, __shfl_xor(M2, k));
        if (h == 0)
            __hip_atomic_store(&pmx[((size_t)img * RR + r2) * NWG + wg], M2,
                               __ATOMIC_RELAXED, __HIP_MEMORY_SCOPE_AGENT);
    }
    img_barrier(myc, (unsigned)NWG * (NITER + 1));
    if (r2 < NR) {
        if (r2 < RR) {
            const float* px = pmx + ((size_t)img * RR + r2) * NWG + h * 4;
            float M = fmaxf(
                fmaxf(__hip_atomic_load(&px[0], __ATOMIC_RELAXED, __HIP_MEMORY_SCOPE_AGENT),
                      __hip_atomic_load(&px[1], __ATOMIC_RELAXED, __HIP_MEMORY_SCOPE_AGENT)),
                fmaxf(__hip_atomic_load(&px[2], __ATOMIC_RELAXED, __HIP_MEMORY_SCOPE_AGENT),
                      __hip_atomic_load(&px[3], __ATOMIC_RELAXED, __HIP_MEMORY_SCOPE_AGENT)));
            #pragma unroll
            for (int k = 1; k < 4; k <<= 1) M = fmaxf(M, __shfl_xor(M, k));
            if (h == 0) sRM[r2] = M;
        } else if (h == 0) sRM[r2] = 1.0f;
    }
    __syncthreads();

    // argmax per column. TRUE DIVISION by rowmax (rowmax cell exactly 1.0,
    // like ref's pi / pi.max); strict > + min-index ties = numpy semantics.
    {
        float bv = -1.0f; int bi = 0x7fffffff;
        #pragma unroll
        for (int i = 0; i < RPT; ++i) {
            int r = r0 + i;
            float pv = p[i] / sRM[r];
            if (r < RR && pv > bv) { bv = pv; bi = r; }
        }
        #pragma unroll
        for (int k = 1; k < 16; k <<= 1) {
            float ov = __shfl_xor(bv, k); int oi = __shfl_xor(bi, k);
            if (ov > bv || (ov == bv && oi < bi)) { bv = ov; bi = oi; }
        }
        if (part == 0 && col < ncols)
            out[(size_t)NIMG * RR * NQI + (size_t)img * NQI + q] = (float)bi;
    }

    // pi output: sA holds p in [row][col]; transpose-read with division by
    // rowmax (broadcast LDS read), 256B coalesced row stores.
    {
        int colj = tid & 63, rl = tid >> 6;
        #pragma unroll
        for (int tt = 0; tt < RPT; ++tt) {
            int rg = rl + 16 * tt;
            if (rg < RR && colj < ncols)
                out[((size_t)img * RR + rg) * NQI + (q0 + colj)] =
                    sA[rg * LDW + colj] / sRM[rg];
        }
    }
}

extern "C" void kernel_launch(void* const* d_in, const int* in_sizes, int n_in,
                              void* d_out, int out_size, void* d_ws, size_t ws_size,
                              hipStream_t stream) {
    const float* logits = (const float*)d_in[0];
    const float* pboxes = (const float*)d_in[1];
    const int*   gcls   = (const int*)  d_in[2];
    const float* gboxes = (const float*)d_in[3];
    const float* imsz   = (const float*)d_in[4];
    const float* imszt  = (const float*)d_in[5];
    float* out = (float*)d_out;

    // layout: cnt 1024 | pmsR (f32) 205,824 | pmsA (8B {m,s}) 411,648.
    // pmx aliases pmsA: pmsA dead after iter-1 combine (99 barriers before
    // pmx's first write) -> race-free reuse.
    unsigned* cnt = (unsigned*)d_ws;
    float* pmsR = (float*)((char*)d_ws + 1024);
    unsigned long long* pmsA =
        (unsigned long long*)((char*)d_ws + 1024 + (size_t)NIMG * RR * NWG * 4);
    float* pmx = (float*)pmsA;

    // only barrier counters need zeroing each call (no tags anymore)
    hipMemsetAsync(d_ws, 0, 1024, stream);

    ota_kernel<<<dim3(256), dim3(NTHR), 0, stream>>>(
        logits, pboxes, gcls, gboxes, imsz, imszt, out, cnt, pmsR, pmsA, pmx);
}